// Round 15
// baseline (328.053 us; speedup 1.0000x reference)
//
#include <hip/hip_runtime.h>
#include <hip/hip_bf16.h>

#define NN 10000
#define NE 160000
#define NZ 10
#define NBES 8
#define NG 16
#define NT 2
#define NB 2048
#define NB1 2049
#define PL ((size_t)NN*64)

static constexpr float PI_F  = 3.14159265358979323846f;
static constexpr float KBES  = 0.63245553203367587f;  // sqrt(2/5)
static constexpr float S3    = 1.73205080756887729f;

// ---- workspace layout (float offsets); node tensors PLANE-MAJOR [k][n][64] ----
static constexpr size_t OFF_UVL  = 0;                        // NE*4 : (ux,uy,uz,L)
static constexpr size_t OFF_PIN  = OFF_UVL + (size_t)NE*4;
static constexpr size_t OFF_ATT  = OFF_PIN + (size_t)NN*3;
static constexpr size_t OFF_CHG  = OFF_ATT + (size_t)NN*NZ;
static constexpr size_t OFF_SHF  = OFF_CHG + (size_t)NN;
static constexpr size_t OFF_NF0  = OFF_SHF + (size_t)NE*3;   // 1 plane (planes 1-3 dead/zero)
static constexpr size_t OFF_NF1  = OFF_NF0 + PL;             // 4 planes
static constexpr size_t OFF_MSG0 = OFF_NF1 + 4*PL;           // 4 planes
static constexpr size_t OFF_MSG1 = OFF_MSG0 + 4*PL;          // 4 planes
static constexpr size_t OFF_AGG  = OFF_MSG1 + 4*PL;          // 4 planes
// aliases (lifetime-disjoint):
//  GA1 -> MSG0 plane 1 (MSG0 planes 1-3 dead after k_tail<t=0>; written by lin2<t=1>)
//  GA0 -> AGG plane 0  (AGG dead after lin2<t=1>; written by k_ghg0)
static constexpr size_t O_GA1    = OFF_MSG0 + PL;
static constexpr size_t O_GA0    = OFF_AGG;
static constexpr size_t OFF_W    = OFF_AGG + 4*PL;
static constexpr size_t O_WEMB   = OFF_W;
static constexpr size_t O_AE     = O_WEMB + 640;
static constexpr size_t O_R1     = O_AE   + 16;
static constexpr size_t O_R2     = O_R1   + 1024;
static constexpr size_t O_WMIX   = O_R2   + 8192;
static constexpr size_t O_WMIXT  = O_WMIX + 24576;
static constexpr size_t O_WSC    = O_WMIXT+ 24576;
static constexpr size_t O_WSCT   = O_WSC  + 24576;
static constexpr size_t O_WPROD  = O_WSCT + 24576;
static constexpr size_t O_WPRODT = O_WPROD+ 24576;
static constexpr size_t O_WPOLY  = O_WPRODT+24576;
static constexpr size_t O_WE     = O_WPOLY+ 384;
static constexpr size_t O_WD     = O_WE   + 128;
static constexpr size_t OFF_ACC  = O_WD   + 128;             // zeroed region start
static constexpr size_t O_E0G    = OFF_ACC;
static constexpr size_t O_ETG    = O_E0G + 16;
static constexpr size_t O_TD     = O_ETG + 32;
static constexpr size_t O_ADP    = O_TD  + 48;
static constexpr size_t O_GPOS   = O_ADP + (size_t)NN*3;
static constexpr size_t ACC_FLOATS = 96 + (size_t)NN*6;      // e0g..gpos
static constexpr size_t O_EN0    = O_GPOS + (size_t)NN*3;
static constexpr size_t O_EN1    = O_EN0 + NN;
static constexpr size_t O_E0N    = O_EN1 + NN;
static constexpr size_t O_FLAG   = O_E0N + NN;
static constexpr size_t O_TW     = O_FLAG + 4;               // pre-scaled by 1/16
static constexpr size_t O_TQ     = O_TW + (size_t)2*NB1*64;  // pre-scaled by 1/16
static constexpr size_t O_OFFR   = O_TQ + (size_t)2*NB1*64;  // ints from here
static constexpr size_t O_OFFS   = O_OFFR + (NN+1);
static constexpr size_t O_CURR   = O_OFFS + (NN+1);
static constexpr size_t O_CURS   = O_CURR + NN;
static constexpr size_t O_RECRAW = O_CURS + NN;
static constexpr size_t O_RECR   = (O_RECRAW + 7) & ~(size_t)7;  // 32B-aligned records
static constexpr size_t O_RECS   = O_RECR + (size_t)NE*8 + 64;   // +64 pad for 8-group over-read
static constexpr size_t WS_FLOATS= O_RECS + (size_t)NE*8 + 64;   // ~62 MB

__device__ __forceinline__ float rlane(float v, int l){
  return __int_as_float(__builtin_amdgcn_readlane(__float_as_int(v), l));
}
__device__ __forceinline__ int irlane(float v, int l){
  return __builtin_amdgcn_readlane(__float_as_int(v), l);
}

// ---------- fused loader (+ dtype detect + workspace zeroing folded in) ----------
static constexpr int LD_CNT[14] = {NN*3, NN*NZ, NN, NE*3, NZ*64, NZ, NT*NBES*64, NT*64*64,
                                   NT*3*64*64, NT*3*64*64, NT*64*3, NT*3*64*64, NT*64, NT*64};
static constexpr int LD_TOTAL = NN*3 + NN*NZ + NN + NE*3 + NZ*64 + NZ + NT*NBES*64 + NT*64*64
                              + 3*(NT*3*64*64) + NT*64*3 + 4*(NT*64) - NT*64*2;
static constexpr int LD_B  = (LD_TOTAL + 255)/256;
static constexpr int Z1_B  = ((int)ACC_FLOATS + 255)/256;   // zero ACC region (floats)
static constexpr int Z2_B  = (2*NN + 255)/256;              // zero curr/curs (ints; same bit pattern)
__global__ __launch_bounds__(256) void k_load_all(
    const void* s0, const void* s1, const void* s2, const void* s3, const void* s4,
    const void* s5, const void* s6, const void* s7, const void* s8, const void* s9,
    const void* s10, const void* s11, const void* s12, const void* s13,
    float* __restrict__ ws){
  if (blockIdx.x >= LD_B){
    int zb = blockIdx.x - LD_B;
    if (zb < Z1_B){
      int i = zb*256 + threadIdx.x;
      if (i < (int)ACC_FLOATS) ws[OFF_ACC + i] = 0.f;
    } else {
      int i = (zb - Z1_B)*256 + threadIdx.x;
      if (i < 2*NN) ((int*)(ws + O_CURR))[i] = 0;
    }
    return;
  }
  __shared__ int found;
  if (threadIdx.x == 0) found = 0;
  __syncthreads();
  const unsigned* raw = (const unsigned*)s1;
  int f = 0;
  for (int i = threadIdx.x; i < 4096; i += 256){
    unsigned w = raw[i];
    f |= (w == 0x00003F80u || w == 0x3F803F80u) ? 1 : 0;
  }
  if (f) found = 1;
  __syncthreads();
  const int isbf = found;
  if (blockIdx.x == 0 && threadIdx.x == 0) ((int*)(ws + O_FLAG))[0] = isbf;

  const void* srcs[14] = {s0,s1,s2,s3,s4,s5,s6,s7,s8,s9,s10,s11,s12,s13};
  const size_t dsts[14] = {OFF_PIN, OFF_ATT, OFF_CHG, OFF_SHF, O_WEMB, O_AE, O_R1, O_R2,
                           O_WMIX, O_WSC, O_WPOLY, O_WPROD, O_WE, O_WD};
  int i = blockIdx.x*256 + threadIdx.x;
  int seg = -1, off = i;
  #pragma unroll
  for (int j = 0; j < 14; ++j){
    if (seg < 0){
      if (off < LD_CNT[j]) seg = j;
      else off -= LD_CNT[j];
    }
  }
  if (seg < 0) return;
  float v = isbf ? __bfloat162float(((const __hip_bfloat16*)srcs[seg])[off])
                 : ((const float*)srcs[seg])[off];
  ws[dsts[seg] + off] = v;
}

// ---------- prep: geometry + live-edge counting only ----------
static constexpr int GEOM_B = (NE+255)/256;   // 625
__global__ __launch_bounds__(256, 3) void k_prep(float* __restrict__ ws, const int* __restrict__ ei){
  int e = blockIdx.x*256 + threadIdx.x;
  if (e >= NE) return;
  const float* pos = ws + OFF_PIN;
  const float* shifts = ws + OFF_SHF;
  int s = ei[e], r = ei[NE + e];
  float vx = pos[s*3+0] - pos[r*3+0] + shifts[(size_t)e*3+0];
  float vy = pos[s*3+1] - pos[r*3+1] + shifts[(size_t)e*3+1];
  float vz = pos[s*3+2] - pos[r*3+2] + shifts[(size_t)e*3+2];
  float L = sqrtf(vx*vx + vy*vy + vz*vz + 1e-12f);
  float inv = 1.f / L;
  float4 uq; uq.x = vx*inv; uq.y = vy*inv; uq.z = vz*inv; uq.w = L;
  *(float4*)(ws + OFF_UVL + (size_t)e*4) = uq;
  if (L < 5.f){
    atomicAdd((int*)(ws + O_CURR) + r, 1);
    atomicAdd((int*)(ws + O_CURS) + s, 1);
  }
}

// ---- scan_plus: block 0 = dual prefix scan (256 thr); rest = tables | node init | transposes ----
// The 1-block scan bubble is hidden behind the independent table/init/transpose work.
static constexpr int TAB_B  = (2*NB1+3)/4;    // 1025
static constexpr int INIT_B = (NN+3)/4;       // 2500
static constexpr int TRAN_B = 5*4096/256;     // 80
static constexpr int SP_TAB0  = 1;
static constexpr int SP_INIT0 = SP_TAB0 + TAB_B;
static constexpr int SP_TRAN0 = SP_INIT0 + INIT_B;
static constexpr int SP_TOTAL = SP_TRAN0 + TRAN_B;   // 3606
__global__ __launch_bounds__(256, 3) void k_scan_plus(float* __restrict__ ws){
  __shared__ unsigned short cr[NN], cs[NN];
  __shared__ int pr[256], ps[256];
  int b = blockIdx.x;
  if (b == 0){
    // ---- dual prefix scan over curr/curs (integer math: exact under re-chunking) ----
    int* curr = (int*)(ws + O_CURR);
    int* curs = (int*)(ws + O_CURS);
    int* offr = (int*)(ws + O_OFFR);
    int* offs_ = (int*)(ws + O_OFFS);
    int tid = threadIdx.x;
    for (int i = tid; i < NN; i += 256){
      cr[i] = (unsigned short)curr[i];
      cs[i] = (unsigned short)curs[i];
    }
    __syncthreads();
    const int chunk = (NN + 255)/256;  // 40
    int lo = tid*chunk, hi = lo + chunk;
    if (hi > NN) hi = NN;
    if (lo > NN) lo = NN;
    int sr = 0, ss = 0;
    for (int i = lo; i < hi; ++i){ sr += cr[i]; ss += cs[i]; }
    pr[tid] = sr; ps[tid] = ss;
    __syncthreads();
    for (int o = 1; o < 256; o <<= 1){
      int vr = (tid >= o) ? pr[tid-o] : 0;
      int vs = (tid >= o) ? ps[tid-o] : 0;
      __syncthreads();
      pr[tid] += vr; ps[tid] += vs;
      __syncthreads();
    }
    int runr = tid ? pr[tid-1] : 0;
    int runs = tid ? ps[tid-1] : 0;
    for (int i = lo; i < hi; ++i){
      int a = cr[i], c = cs[i];
      offr[i] = runr; curr[i] = runr; runr += a;
      offs_[i] = runs; curs[i] = runs; runs += c;
    }
    if (tid == 255){ offr[NN] = runr; offs_[NN] = runs; }
    return;
  }
  if (b < SP_INIT0){
    // ---- radial tables ----
    int lane = threadIdx.x & 63;
    int task = (b - SP_TAB0)*4 + (threadIdx.x >> 6);
    if (task >= 2*NB1) return;
    int t = task / NB1, node = task % NB1;
    const float* R1 = ws + O_R1 + (size_t)t*512;
    const float* R2 = ws + O_R2 + (size_t)t*4096;
    float r1c[8];
    #pragma unroll
    for (int j = 0; j < 8; ++j) r1c[j] = R1[j*64 + lane];
    float L = fmaxf((float)node * (5.f/NB), 1e-6f);
    float ur = L*0.2f;
    float ef[8], dd[8];
    if (ur < 1.f){
      float u2=ur*ur, u4=u2*u2, u5=u4*ur;
      float fc = 1.f - 21.f*u5 + 35.f*u5*ur - 15.f*u5*u2;
      float omu = 1.f - ur;
      float dfc = -105.f*u4*omu*omu;
      float invr = 1.f/(L + 1e-9f);
      #pragma unroll
      for (int bb = 0; bb < 8; ++bb){
        float nb = (float)(bb+1);
        float arg = nb*PI_F*ur;
        float sn = __sinf(arg), cs2 = __cosf(arg);
        float bes = KBES*sn*invr;
        float dbes = KBES*(nb*PI_F*0.2f)*cs2*invr - bes*invr;
        ef[bb] = bes*fc;
        dd[bb] = dbes*fc + bes*dfc*0.2f;
      }
    } else {
      #pragma unroll
      for (int bb = 0; bb < 8; ++bb){ ef[bb] = 0.f; dd[bb] = 0.f; }
    }
    float a = 0.f, tt = 0.f;
    #pragma unroll
    for (int bb = 0; bb < 8; ++bb){ a = fmaf(ef[bb], r1c[bb], a); tt = fmaf(r1c[bb], dd[bb], tt); }
    float sg = 1.f/(1.f + __expf(-a));
    float sl = a*sg;
    float q  = sg*fmaf(a, 1.f - sg, 1.f)*tt;
    float r2c[64];
    #pragma unroll
    for (int j = 0; j < 64; ++j) r2c[j] = R2[j*64 + lane];
    float W0=0.f, W1=0.f, Q0=0.f, Q1=0.f;
    #pragma unroll
    for (int j = 0; j < 64; j += 2){
      W0 = fmaf(rlane(sl, j  ), r2c[j  ], W0);
      W1 = fmaf(rlane(sl, j+1), r2c[j+1], W1);
      Q0 = fmaf(rlane(q,  j  ), r2c[j  ], Q0);
      Q1 = fmaf(rlane(q,  j+1), r2c[j+1], Q1);
    }
    size_t idx = ((size_t)t*NB1 + node)*64 + lane;
    ws[O_TW + idx] = (W0+W1)*(1.f/16.f);   // fold /AVG_NEIGH into table
    ws[O_TQ + idx] = (Q0+Q1)*(1.f/16.f);
  } else if (b < SP_TRAN0){
    // ---- node init ----
    int lane = threadIdx.x & 63;
    int n = (b - SP_INIT0)*4 + (threadIdx.x >> 6);
    if (n >= NN) return;
    const float* attrs = ws + OFF_ATT;
    float acc = 0.f;
    #pragma unroll
    for (int z = 0; z < NZ; ++z) acc = fmaf(attrs[(size_t)n*NZ+z], ws[O_WEMB + z*64 + lane], acc);
    ws[OFF_NF0 + (size_t)n*64 + lane] = acc;
    if (lane == 0){
      float e = 0.f;
      #pragma unroll
      for (int z = 0; z < NZ; ++z) e = fmaf(attrs[(size_t)n*NZ+z], ws[O_AE + z], e);
      ws[O_E0N + n] = e;
    }
  } else {
    // ---- 5 transposed matrices ----
    int i = (b - SP_TRAN0)*256 + threadIdx.x;   // 0..20479
    int mat = i >> 12, r = (i >> 6) & 63, c = i & 63;
    const size_t src[5] = {O_WMIX, O_WMIX+12288, O_WPROD, O_WPROD+12288, O_WSC+12288};
    const size_t dst[5] = {O_WMIXT, O_WMIXT+12288, O_WPRODT, O_WPRODT+12288, O_WSCT+12288};
    ws[dst[mat] + (size_t)c*64 + r] = ws[src[mat] + (size_t)r*64 + c];
  }
}

// ---------- fill: live edges only, 32B packed records {ux,uy,uz,L,s,r,e,pad} ----------
__global__ void k_csr_fill(const int* __restrict__ ei, const float* __restrict__ uvl,
                           int* __restrict__ curr, int* __restrict__ curs,
                           float* __restrict__ recr, float* __restrict__ recs){
  int e = blockIdx.x*256 + threadIdx.x;
  if (e >= NE) return;
  float4 q = *(const float4*)(uvl + (size_t)e*4);
  if (q.w >= 5.f) return;
  int s = ei[e], r = ei[NE + e];
  int4 meta; meta.x = s; meta.y = r; meta.z = e; meta.w = 0;
  int pr = atomicAdd(&curr[r], 1);
  *(float4*)(recr + (size_t)pr*8) = q;
  *(int4*)(recr + (size_t)pr*8 + 4) = meta;
  int ps = atomicAdd(&curs[s], 1);
  *(float4*)(recs + (size_t)ps*8) = q;
  *(int4*)(recs + (size_t)ps*8 + 4) = meta;
}

// ================= aggregation: 8-record coalesced group loads + readlane broadcast =================
__global__ __launch_bounds__(256) void k_agg(
    const float* __restrict__ TWt, const float* __restrict__ recr,
    const float* __restrict__ h, const int* __restrict__ offr,
    float* __restrict__ agg){
  int lane = threadIdx.x & 63;
  int wid = blockIdx.x*4 + (threadIdx.x >> 6);
  int nw  = gridDim.x*4;
  for (int n = wid; n < NN; n += nw){
    int lo = offr[n], hi = offr[n+1];
    float c0=0.f, x1=0.f, y1=0.f, z1=0.f;
    for (int i = lo; i < hi; i += 8){
      float rv = recr[(size_t)i*8 + lane];   // 8 records = 64 floats, coalesced
      int cnt = hi - i;
      if (cnt >= 8){
        #pragma unroll
        for (int j = 0; j < 8; ++j){
          float ux = rlane(rv, j*8+0), uy = rlane(rv, j*8+1), uz = rlane(rv, j*8+2);
          float L  = rlane(rv, j*8+3);
          int   s  = irlane(rv, j*8+4);
          float pos = L*(NB/5.f); int bi = (int)pos; float f = pos - (float)bi;
          const float* T = TWt + (size_t)bi*64 + lane;
          float t0 = T[0];
          float w = fmaf(T[64]-t0, f, t0);
          float wh = w * h[(size_t)s*64 + lane];
          c0 += wh;
          x1 = fmaf(wh, ux, x1);
          y1 = fmaf(wh, uy, y1);
          z1 = fmaf(wh, uz, z1);
        }
      } else {
        for (int j = 0; j < cnt; ++j){
          float ux = rlane(rv, j*8+0), uy = rlane(rv, j*8+1), uz = rlane(rv, j*8+2);
          float L  = rlane(rv, j*8+3);
          int   s  = irlane(rv, j*8+4);
          float pos = L*(NB/5.f); int bi = (int)pos; float f = pos - (float)bi;
          const float* T = TWt + (size_t)bi*64 + lane;
          float t0 = T[0];
          float w = fmaf(T[64]-t0, f, t0);
          float wh = w * h[(size_t)s*64 + lane];
          c0 += wh;
          x1 = fmaf(wh, ux, x1);
          y1 = fmaf(wh, uy, y1);
          z1 = fmaf(wh, uz, z1);
        }
      }
    }
    size_t ob = (size_t)n*64 + lane;
    agg[ob]        = c0;               // table pre-scaled by 1/16
    agg[ob+PL]     = S3*x1;
    agg[ob+2*PL]   = S3*y1;
    agg[ob+3*PL]   = S3*z1;
  }
}

// ================= per-l linear (mix), plane-major; GB1 fuses t=1 gback into y==0 =================
template<int GB1>
__global__ __launch_bounds__(256, 3) void k_lin2(
    const float* __restrict__ in, const float* __restrict__ W3, float* __restrict__ out,
    const float* __restrict__ WMIXT1, const float* __restrict__ WPRODT1,
    const float* __restrict__ we1, const float* __restrict__ wp1,
    float* __restrict__ ga1){
  int k = blockIdx.y;
  int l = (k==0) ? 0 : 1;
  const float* W = W3 + (size_t)l*4096;
  int lane = threadIdx.x & 63;
  float wcol[64];
  #pragma unroll
  for (int j = 0; j < 64; ++j) wcol[j] = W[j*64 + lane];
  float wcol2[64];
  float g = 0.f, p0 = 0.f, p1 = 0.f, p2 = 0.f;
  const bool gb1 = GB1 && (k == 0);
  if (gb1){
    #pragma unroll
    for (int j = 0; j < 64; ++j) wcol2[j] = WMIXT1[j*64 + lane];
    #pragma unroll
    for (int c = 0; c < 64; ++c) g = fmaf(we1[c], WPRODT1[c*64 + lane], g);
    p0 = wp1[lane*3]; p1 = wp1[lane*3+1]; p2 = wp1[lane*3+2];
  }
  int wid = blockIdx.x*4 + (threadIdx.x >> 6);
  int nw  = gridDim.x*4;
  const float* inp = in + (size_t)k*PL;
  float* outp = out + (size_t)k*PL;
  for (int n = wid; n < NN; n += nw){
    float x = inp[(size_t)n*64 + lane];
    float a0 = 0.f, a1 = 0.f, a2 = 0.f, a3 = 0.f;
    #pragma unroll
    for (int j = 0; j < 64; j += 4){
      a0 = fmaf(rlane(x, j  ), wcol[j  ], a0);
      a1 = fmaf(rlane(x, j+1), wcol[j+1], a1);
      a2 = fmaf(rlane(x, j+2), wcol[j+2], a2);
      a3 = fmaf(rlane(x, j+3), wcol[j+3], a3);
    }
    float m = (a0+a1) + (a2+a3);
    outp[(size_t)n*64 + lane] = m;
    if (gb1){
      // fused gback1: GA1 = (g * d/ds0[s0*poly(s0)]) @ WMIXT1, s0 = m
      float poly = fmaf(fmaf(p2, m, p1), m, p0);
      float dp   = fmaf(2.f*p2, m, p1);
      float gb = g*fmaf(m, dp, poly);
      float b0=0.f, b1=0.f, b2=0.f, b3=0.f;
      #pragma unroll
      for (int j = 0; j < 64; j += 4){
        b0 = fmaf(rlane(gb, j  ), wcol2[j  ], b0);
        b1 = fmaf(rlane(gb, j+1), wcol2[j+1], b1);
        b2 = fmaf(rlane(gb, j+2), wcol2[j+2], b2);
        b3 = fmaf(rlane(gb, j+3), wcol2[j+3], b3);
      }
      ga1[(size_t)n*64 + lane] = (b0+b1) + (b2+b3);
    }
  }
}

// ================= fused layer tail (plane-major; compile-time variants) =================
template<int WRITE_NF, int NF_SINGLE>
__global__ __launch_bounds__(256, 3) void k_tail(
    const float* __restrict__ nf_in, const float* __restrict__ msg,
    const float* __restrict__ Wsc, const float* __restrict__ Wprod, const float* __restrict__ wp,
    const float* __restrict__ we, const float* __restrict__ wd,
    float* __restrict__ nf_out, float* __restrict__ en, float* __restrict__ adp){
  int lane = threadIdx.x & 63;
  int k = threadIdx.x >> 6;
  int l = (k==0) ? 0 : 1;
  const bool use_sc = !(NF_SINGLE && k > 0);
  float wcs[64], wcp[64];
  #pragma unroll
  for (int j = 0; j < 64; ++j)
    wcp[j] = Wprod[(size_t)l*4096 + j*64 + lane];
  if (use_sc){
    #pragma unroll
    for (int j = 0; j < 64; ++j)
      wcs[j] = Wsc[(size_t)l*4096 + j*64 + lane];
  }
  float p0 = wp[lane*3], p1 = wp[lane*3+1], p2 = wp[lane*3+2];
  float rw = (k==0) ? we[lane] : wd[lane];
  const float* msgk = msg + (size_t)k*PL;
  const float* nfk  = nf_in + (size_t)k*PL;
  float* outk = nf_out + (size_t)k*PL;
  for (int n = blockIdx.x; n < NN; n += gridDim.x){
    size_t base = (size_t)n*64 + lane;
    float s0 = msg[base];
    float xm = (k==0) ? s0 : msgk[base];
    float xg = xm * fmaf(fmaf(p2, s0, p1), s0, p0);
    float b0=0.f, b1=0.f;
    #pragma unroll
    for (int j = 0; j < 64; j += 2){
      b0 = fmaf(rlane(xg, j  ), wcp[j  ], b0);
      b1 = fmaf(rlane(xg, j+1), wcp[j+1], b1);
    }
    float out = b0 + b1;
    if (use_sc){
      float xs = nfk[base];
      float a0=0.f, a1=0.f;
      #pragma unroll
      for (int j = 0; j < 64; j += 2){
        a0 = fmaf(rlane(xs, j  ), wcs[j  ], a0);
        a1 = fmaf(rlane(xs, j+1), wcs[j+1], a1);
      }
      out += a0 + a1;
    }
    if (WRITE_NF) outk[base] = out;
    float red = out * rw;
    #pragma unroll
    for (int o = 32; o; o >>= 1) red += __shfl_xor(red, o, 64);
    if (lane == 0){
      if (k == 0) en[n] = red;
      else        adp[n*3 + (k-1)] += red;
    }
  }
}

// ================= fused ghgather0 + gback0 (+ bwd_head) + segmented reduce =================
static constexpr int GHG_GRID = 1024;
static constexpr int RED_B = (NN+255)/256;    // 40
__global__ __launch_bounds__(256) void k_ghg0(float* __restrict__ ws, const int* __restrict__ offs_,
                                              const int* __restrict__ batch){
  __shared__ float wl[2*4096];   // [0]=WPRODT0 l0, [1]=WMIXT0 l0
  if (blockIdx.x >= GHG_GRID){
    // ---- folded k_reduce (inputs ready after k_tail<t=1>) ----
    int n = (blockIdx.x - GHG_GRID)*256 + threadIdx.x;
    int lane = threadIdx.x & 63;
    bool valid = (n < NN);
    int g = valid ? batch[n] : -1;
    float v0=0.f, v1=0.f, v2=0.f, tx=0.f, ty=0.f, tz=0.f;
    if (valid){
      v0 = ws[O_E0N + n]; v1 = ws[O_EN0 + n]; v2 = ws[O_EN1 + n];
      float qq = ws[OFF_CHG + n];
      tx = ws[O_ADP + n*3+0] + qq*ws[OFF_PIN + n*3+0];
      ty = ws[O_ADP + n*3+1] + qq*ws[OFF_PIN + n*3+1];
      tz = ws[O_ADP + n*3+2] + qq*ws[OFF_PIN + n*3+2];
    }
    float* e0g = ws + O_E0G; float* Etg = ws + O_ETG; float* td = ws + O_TD;
    int g0 = __shfl(g, 0, 64), g63 = __shfl(g, 63, 64);
    if (g0 == g63 && g0 >= 0){
      #pragma unroll
      for (int o = 32; o; o >>= 1){
        v0 += __shfl_xor(v0, o, 64); v1 += __shfl_xor(v1, o, 64); v2 += __shfl_xor(v2, o, 64);
        tx += __shfl_xor(tx, o, 64); ty += __shfl_xor(ty, o, 64); tz += __shfl_xor(tz, o, 64);
      }
      if (lane == 0){
        atomicAdd(&e0g[g0], v0); atomicAdd(&Etg[g0], v1); atomicAdd(&Etg[16+g0], v2);
        atomicAdd(&td[g0*3+0], tx); atomicAdd(&td[g0*3+1], ty); atomicAdd(&td[g0*3+2], tz);
      }
    } else if (valid){
      atomicAdd(&e0g[g], v0); atomicAdd(&Etg[g], v1); atomicAdd(&Etg[16+g], v2);
      atomicAdd(&td[g*3+0], tx); atomicAdd(&td[g*3+1], ty); atomicAdd(&td[g*3+2], tz);
    }
    return;
  }
  for (int i = threadIdx.x; i < 4096; i += 256){
    wl[i]        = ws[O_WPRODT + i];
    wl[4096 + i] = ws[O_WMIXT + i];
  }
  __syncthreads();
  const int lane = threadIdx.x & 63;
  int wid = blockIdx.x*4 + (threadIdx.x >> 6);
  const int nw = GHG_GRID*4;
  // gnfc = we0 + WSCT1 @ we1  (folded bwd_head)
  float gnfc = ws[O_WE + lane];
  {
    const float* WS1 = ws + O_WSCT + 12288;
    const float* we1 = ws + O_WE + 64;
    #pragma unroll
    for (int c = 0; c < 64; ++c) gnfc = fmaf(we1[c], WS1[c*64 + lane], gnfc);
  }
  const float p0 = ws[O_WPOLY + lane*3];
  const float p1 = ws[O_WPOLY + lane*3 + 1];
  const float p2 = ws[O_WPOLY + lane*3 + 2];
  const float* TW1 = ws + O_TW + (size_t)NB1*64;  // t=1 table (pre-scaled 1/16)
  const float* recs = ws + O_RECS;
  const float* GA1 = ws + O_GA1;
  for (int n = wid; n < NN; n += nw){
    int lo = offs_[n], hi = offs_[n+1];
    float acc = 0.f;
    for (int i = lo; i < hi; i += 8){
      float rv = recs[(size_t)i*8 + lane];   // 8 records coalesced
      int cnt = hi - i;
      if (cnt >= 8){
        #pragma unroll
        for (int j = 0; j < 8; ++j){
          float L = rlane(rv, j*8+3);
          int   r = irlane(rv, j*8+5);
          float pos = L*(NB/5.f); int bi = (int)pos; float f = pos - (float)bi;
          const float* T = TW1 + (size_t)bi*64 + lane;
          float t0 = T[0];
          float w = fmaf(T[64]-t0, f, t0);
          acc = fmaf(w, GA1[(size_t)r*64 + lane], acc);
        }
      } else {
        for (int j = 0; j < cnt; ++j){
          float L = rlane(rv, j*8+3);
          int   r = irlane(rv, j*8+5);
          float pos = L*(NB/5.f); int bi = (int)pos; float f = pos - (float)bi;
          const float* T = TW1 + (size_t)bi*64 + lane;
          float t0 = T[0];
          float w = fmaf(T[64]-t0, f, t0);
          acc = fmaf(w, GA1[(size_t)r*64 + lane], acc);
        }
      }
    }
    float gB = gnfc + acc;                // table pre-scaled by 1/16
    float q0=0.f, q1=0.f;
    #pragma unroll
    for (int j = 0; j < 64; j += 2){
      q0 = fmaf(rlane(gB,j),   wl[j*64 + lane],     q0);
      q1 = fmaf(rlane(gB,j+1), wl[(j+1)*64 + lane], q1);
    }
    float gmp = q0 + q1;
    float s0v = ws[OFF_MSG0 + (size_t)n*64 + lane];
    float poly = fmaf(fmaf(p2, s0v, p1), s0v, p0);
    float dp   = fmaf(2.f*p2, s0v, p1);
    float gb = gmp * fmaf(s0v, dp, poly);
    float u0=0.f, u1=0.f;
    #pragma unroll
    for (int j = 0; j < 64; j += 2){
      u0 = fmaf(rlane(gb,j),   wl[4096 + j*64 + lane],     u0);
      u1 = fmaf(rlane(gb,j+1), wl[4096 + (j+1)*64 + lane], u1);
    }
    ws[O_GA0 + (size_t)n*64 + lane] = u0 + u1;
  }
}

// ================= fused edge backward + force scatter: 8-edge groups =================
__global__ __launch_bounds__(256) void k_bwdE2(float* __restrict__ ws, const int* __restrict__ nlive_ptr){
  const int lane = threadIdx.x & 63;
  int wid = blockIdx.x*4 + (threadIdx.x >> 6);
  const int nw = gridDim.x*4;
  const int nlive = nlive_ptr[0];
  const int ngrp = (nlive + 7) >> 3;
  const float* recs = ws + O_RECS;
  const float* TQ  = ws + O_TQ;     // pre-scaled 1/16
  const float* h0  = ws + OFF_NF0;
  const float* h1  = ws + OFF_NF1;  // plane 0
  const float* ga0 = ws + O_GA0;
  const float* ga1 = ws + O_GA1;
  float* gpos = ws + O_GPOS;
  for (int gi = wid; gi < ngrp; gi += nw){
    const int i0 = gi*8;
    float rv = recs[(size_t)i0*8 + lane];   // 8 records coalesced
    int cnt = nlive - i0; if (cnt > 8) cnt = 8;
    #pragma unroll 8
    for (int j = 0; j < cnt; ++j){
      float ux = rlane(rv, j*8+0), uy = rlane(rv, j*8+1), uz = rlane(rv, j*8+2);
      float L  = rlane(rv, j*8+3);
      int   s  = irlane(rv, j*8+4);
      int   r  = irlane(rv, j*8+5);
      float pos = L*(NB/5.f); int bi = (int)pos; float f = pos - (float)bi;
      const float* T0 = TQ + (size_t)bi*64 + lane;
      const float* T1 = T0 + (size_t)NB1*64;
      float Q0 = fmaf(T0[64]-T0[0], f, T0[0]);
      float Q1 = fmaf(T1[64]-T1[0], f, T1[0]);
      float rr = Q0*h0[(size_t)s*64 + lane]*ga0[(size_t)r*64 + lane]
               + Q1*h1[(size_t)s*64 + lane]*ga1[(size_t)r*64 + lane];
      #pragma unroll
      for (int o = 32; o; o >>= 1) rr += __shfl_xor(rr, o, 64);
      if (lane < 3){
        float u = (lane==0) ? ux : ((lane==1) ? uy : uz);
        float v = rr*u;
        atomicAdd(&gpos[(size_t)s*3 + lane],  v);
        atomicAdd(&gpos[(size_t)r*3 + lane], -v);
      }
    }
  }
}

__global__ void k_writeout(const float* __restrict__ e0g, const float* __restrict__ Etg,
                           const float* __restrict__ td, const float* __restrict__ adp,
                           const float* __restrict__ gpos, void* __restrict__ outv,
                           const int* __restrict__ flag){
  int i = blockIdx.x*256 + threadIdx.x;
  const int total = NG + NG*3 + NN*3 + NG*3 + NN*3; // 60112
  if (i >= total) return;
  float v;
  if (i < 16){
    v = e0g[i] + Etg[i] + Etg[16+i];
  } else if (i < 64){
    int j = i - 16; int g = j/3, t = j - g*3;
    v = (t == 0) ? e0g[g] : Etg[(t-1)*16 + g];
  } else if (i < 64 + NN*3){
    v = -gpos[i-64];
  } else if (i < 64 + NN*3 + 48){
    v = td[i - (64 + NN*3)];
  } else {
    v = adp[i - (64 + NN*3 + 48)];
  }
  if (flag[0]) ((__hip_bfloat16*)outv)[i] = __float2bfloat16(v);
  else         ((float*)outv)[i] = v;
}

extern "C" void kernel_launch(void* const* d_in, const int* in_sizes, int n_in,
                              void* d_out, int out_size, void* d_ws, size_t ws_size,
                              hipStream_t stream) {
  if (ws_size < WS_FLOATS*sizeof(float)) return; // ~62 MB
  const int* ei    = (const int*)d_in[14];
  const int* batch = (const int*)d_in[15];
  float* ws = (float*)d_ws;

  int* offr  = (int*)(ws + O_OFFR);
  int* offs_ = (int*)(ws + O_OFFS);
  int* curr  = (int*)(ws + O_CURR);
  int* curs  = (int*)(ws + O_CURS);

  // workspace zeroing folded into k_load_all's tail blocks (no memset dispatches)
  k_load_all<<<LD_B + Z1_B + Z2_B, 256, 0, stream>>>(
      d_in[0], d_in[1], d_in[2], d_in[3], d_in[4], d_in[5], d_in[6], d_in[7],
      d_in[8], d_in[9], d_in[10], d_in[11], d_in[12], d_in[13], ws);
  k_prep<<<GEOM_B, 256, 0, stream>>>(ws, ei);
  // scan (1 block) co-scheduled with tables/init/transposes -> bubble hidden
  k_scan_plus<<<SP_TOTAL, 256, 0, stream>>>(ws);
  k_csr_fill<<<(NE+255)/256, 256, 0, stream>>>(ei, ws+OFF_UVL, curr, curs,
                                               ws+O_RECR, ws+O_RECS);

  dim3 ling(256, 4);

  // ---------- forward t=0 ----------
  k_agg<<<1024, 256, 0, stream>>>(ws+O_TW, ws+O_RECR, ws+OFF_NF0, offr, ws+OFF_AGG);
  k_lin2<0><<<ling, 256, 0, stream>>>(ws+OFF_AGG, ws+O_WMIX, ws+OFF_MSG0,
                                      ws, ws, ws, ws, ws);
  k_tail<1,1><<<1024, 256, 0, stream>>>(ws+OFF_NF0, ws+OFF_MSG0,
                                        ws+O_WSC, ws+O_WPROD,
                                        ws+O_WPOLY, ws+O_WE, ws+O_WD,
                                        ws+OFF_NF1, ws+O_EN0, ws+O_ADP);
  // ---------- forward t=1 (+ fused gback1 in y==0) ----------
  k_agg<<<1024, 256, 0, stream>>>(ws+O_TW + (size_t)NB1*64, ws+O_RECR, ws+OFF_NF1, offr, ws+OFF_AGG);
  k_lin2<1><<<ling, 256, 0, stream>>>(ws+OFF_AGG, ws+O_WMIX + 12288, ws+OFF_MSG1,
                                      ws+O_WMIXT + 12288, ws+O_WPRODT + 12288,
                                      ws+O_WE + 64, ws+O_WPOLY + 192, ws+O_GA1);
  k_tail<0,0><<<1024, 256, 0, stream>>>(ws+OFF_NF1, ws+OFF_MSG1,
                                        ws+O_WSC + 12288, ws+O_WPROD + 12288,
                                        ws+O_WPOLY + 192, ws+O_WE + 64, ws+O_WD + 64,
                                        ws+OFF_NF1, ws+O_EN1, ws+O_ADP);

  // ---------- backward ----------
  k_ghg0<<<GHG_GRID + RED_B, 256, 0, stream>>>(ws, offs_, batch);
  k_bwdE2<<<2048, 256, 0, stream>>>(ws, offs_ + NN);

  k_writeout<<<(60112+255)/256, 256, 0, stream>>>(ws+O_E0G, ws+O_ETG, ws+O_TD, ws+O_ADP,
                                                  ws+O_GPOS, d_out, (const int*)(ws+O_FLAG));
}

// Round 16
// 324.190 us; speedup vs baseline: 1.0119x; 1.0119x over previous
//
#include <hip/hip_runtime.h>
#include <hip/hip_bf16.h>

#define NN 10000
#define NE 160000
#define NZ 10
#define NBES 8
#define NG 16
#define NT 2
#define NB 2048
#define NB1 2049
#define PL ((size_t)NN*64)

static constexpr float PI_F  = 3.14159265358979323846f;
static constexpr float KBES  = 0.63245553203367587f;  // sqrt(2/5)
static constexpr float S3    = 1.73205080756887729f;

// ---- workspace layout (float offsets); node tensors PLANE-MAJOR [k][n][64] ----
static constexpr size_t OFF_UVL  = 0;                        // NE*4 : (ux,uy,uz,L)
static constexpr size_t OFF_PIN  = OFF_UVL + (size_t)NE*4;
static constexpr size_t OFF_ATT  = OFF_PIN + (size_t)NN*3;
static constexpr size_t OFF_CHG  = OFF_ATT + (size_t)NN*NZ;
static constexpr size_t OFF_SHF  = OFF_CHG + (size_t)NN;
static constexpr size_t OFF_NF0  = OFF_SHF + (size_t)NE*3;   // 1 plane (planes 1-3 dead/zero)
static constexpr size_t OFF_NF1  = OFF_NF0 + PL;             // 4 planes
static constexpr size_t OFF_MSG0 = OFF_NF1 + 4*PL;           // 4 planes
static constexpr size_t OFF_MSG1 = OFF_MSG0 + 4*PL;          // 4 planes
static constexpr size_t OFF_AGG  = OFF_MSG1 + 4*PL;          // 4 planes
// aliases (lifetime-disjoint):
//  GA1 -> MSG0 plane 1 (MSG0 planes 1-3 dead after k_tail<t=0>; written by lin2<t=1>)
//  GA0 -> AGG plane 0  (AGG dead after lin2<t=1>; written by k_ghg0)
static constexpr size_t O_GA1    = OFF_MSG0 + PL;
static constexpr size_t O_GA0    = OFF_AGG;
static constexpr size_t OFF_W    = OFF_AGG + 4*PL;
static constexpr size_t O_WEMB   = OFF_W;
static constexpr size_t O_AE     = O_WEMB + 640;
static constexpr size_t O_R1     = O_AE   + 16;
static constexpr size_t O_R2     = O_R1   + 1024;
static constexpr size_t O_WMIX   = O_R2   + 8192;
static constexpr size_t O_WMIXT  = O_WMIX + 24576;
static constexpr size_t O_WSC    = O_WMIXT+ 24576;
static constexpr size_t O_WSCT   = O_WSC  + 24576;
static constexpr size_t O_WPROD  = O_WSCT + 24576;
static constexpr size_t O_WPRODT = O_WPROD+ 24576;
static constexpr size_t O_WPOLY  = O_WPRODT+24576;
static constexpr size_t O_WE     = O_WPOLY+ 384;
static constexpr size_t O_WD     = O_WE   + 128;
static constexpr size_t OFF_ACC  = O_WD   + 128;             // zeroed region start
static constexpr size_t O_E0G    = OFF_ACC;
static constexpr size_t O_ETG    = O_E0G + 16;
static constexpr size_t O_TD     = O_ETG + 32;
static constexpr size_t O_ADP    = O_TD  + 48;
static constexpr size_t O_GPOS   = O_ADP + (size_t)NN*3;
static constexpr size_t ACC_FLOATS = 96 + (size_t)NN*6;      // e0g..gpos
static constexpr size_t O_EN0    = O_GPOS + (size_t)NN*3;
static constexpr size_t O_EN1    = O_EN0 + NN;
static constexpr size_t O_E0N    = O_EN1 + NN;
static constexpr size_t O_FLAG   = O_E0N + NN;
static constexpr size_t O_TW     = O_FLAG + 4;               // pre-scaled by 1/16
static constexpr size_t O_TQ     = O_TW + (size_t)2*NB1*64;  // pre-scaled by 1/16
static constexpr size_t O_OFFR   = O_TQ + (size_t)2*NB1*64;  // ints from here
static constexpr size_t O_OFFS   = O_OFFR + (NN+1);
static constexpr size_t O_CURR   = O_OFFS + (NN+1);
static constexpr size_t O_CURS   = O_CURR + NN;
static constexpr size_t O_RECRAW = O_CURS + NN;
static constexpr size_t O_RECR   = (O_RECRAW + 7) & ~(size_t)7;  // 32B-aligned records
static constexpr size_t O_RECS   = O_RECR + (size_t)NE*8 + 64;   // +64 pad for 8-group over-read
static constexpr size_t WS_FLOATS= O_RECS + (size_t)NE*8 + 64;   // ~62 MB

__device__ __forceinline__ float rlane(float v, int l){
  return __int_as_float(__builtin_amdgcn_readlane(__float_as_int(v), l));
}
__device__ __forceinline__ int irlane(float v, int l){
  return __builtin_amdgcn_readlane(__float_as_int(v), l);
}

// ---------- fused loader (+ dtype detect + workspace zeroing folded in) ----------
static constexpr int LD_CNT[14] = {NN*3, NN*NZ, NN, NE*3, NZ*64, NZ, NT*NBES*64, NT*64*64,
                                   NT*3*64*64, NT*3*64*64, NT*64*3, NT*3*64*64, NT*64, NT*64};
static constexpr int LD_TOTAL = NN*3 + NN*NZ + NN + NE*3 + NZ*64 + NZ + NT*NBES*64 + NT*64*64
                              + 3*(NT*3*64*64) + NT*64*3 + 4*(NT*64) - NT*64*2;
static constexpr int LD_B  = (LD_TOTAL + 255)/256;
static constexpr int Z1_B  = ((int)ACC_FLOATS + 255)/256;   // zero ACC region (floats)
static constexpr int Z2_B  = (2*NN + 255)/256;              // zero curr/curs (ints; same bit pattern)
__global__ __launch_bounds__(256) void k_load_all(
    const void* s0, const void* s1, const void* s2, const void* s3, const void* s4,
    const void* s5, const void* s6, const void* s7, const void* s8, const void* s9,
    const void* s10, const void* s11, const void* s12, const void* s13,
    float* __restrict__ ws){
  if (blockIdx.x >= LD_B){
    int zb = blockIdx.x - LD_B;
    if (zb < Z1_B){
      int i = zb*256 + threadIdx.x;
      if (i < (int)ACC_FLOATS) ws[OFF_ACC + i] = 0.f;
    } else {
      int i = (zb - Z1_B)*256 + threadIdx.x;
      if (i < 2*NN) ((int*)(ws + O_CURR))[i] = 0;
    }
    return;
  }
  __shared__ int found;
  if (threadIdx.x == 0) found = 0;
  __syncthreads();
  const unsigned* raw = (const unsigned*)s1;
  int f = 0;
  for (int i = threadIdx.x; i < 4096; i += 256){
    unsigned w = raw[i];
    f |= (w == 0x00003F80u || w == 0x3F803F80u) ? 1 : 0;
  }
  if (f) found = 1;
  __syncthreads();
  const int isbf = found;
  if (blockIdx.x == 0 && threadIdx.x == 0) ((int*)(ws + O_FLAG))[0] = isbf;

  const void* srcs[14] = {s0,s1,s2,s3,s4,s5,s6,s7,s8,s9,s10,s11,s12,s13};
  const size_t dsts[14] = {OFF_PIN, OFF_ATT, OFF_CHG, OFF_SHF, O_WEMB, O_AE, O_R1, O_R2,
                           O_WMIX, O_WSC, O_WPOLY, O_WPROD, O_WE, O_WD};
  int i = blockIdx.x*256 + threadIdx.x;
  int seg = -1, off = i;
  #pragma unroll
  for (int j = 0; j < 14; ++j){
    if (seg < 0){
      if (off < LD_CNT[j]) seg = j;
      else off -= LD_CNT[j];
    }
  }
  if (seg < 0) return;
  float v = isbf ? __bfloat162float(((const __hip_bfloat16*)srcs[seg])[off])
                 : ((const float*)srcs[seg])[off];
  ws[dsts[seg] + off] = v;
}

// ---------- fused prep: geom+count | radial tables | node init | 5 transposes ----------
static constexpr int GEOM_B = (NE+255)/256;   // 625
static constexpr int TAB_B  = (2*NB1+3)/4;    // 1025
static constexpr int INIT_B = (NN+3)/4;       // 2500
static constexpr int TRAN_B = 5*4096/256;     // 80
__global__ __launch_bounds__(256, 3) void k_prep(float* __restrict__ ws, const int* __restrict__ ei){
  int b = blockIdx.x;
  if (b < GEOM_B){
    int e = b*256 + threadIdx.x;
    if (e >= NE) return;
    const float* pos = ws + OFF_PIN;
    const float* shifts = ws + OFF_SHF;
    int s = ei[e], r = ei[NE + e];
    float vx = pos[s*3+0] - pos[r*3+0] + shifts[(size_t)e*3+0];
    float vy = pos[s*3+1] - pos[r*3+1] + shifts[(size_t)e*3+1];
    float vz = pos[s*3+2] - pos[r*3+2] + shifts[(size_t)e*3+2];
    float L = sqrtf(vx*vx + vy*vy + vz*vz + 1e-12f);
    float inv = 1.f / L;
    float4 uq; uq.x = vx*inv; uq.y = vy*inv; uq.z = vz*inv; uq.w = L;
    *(float4*)(ws + OFF_UVL + (size_t)e*4) = uq;
    if (L < 5.f){
      atomicAdd((int*)(ws + O_CURR) + r, 1);
      atomicAdd((int*)(ws + O_CURS) + s, 1);
    }
  } else if (b < GEOM_B + TAB_B){
    int lane = threadIdx.x & 63;
    int task = (b - GEOM_B)*4 + (threadIdx.x >> 6);
    if (task >= 2*NB1) return;
    int t = task / NB1, node = task % NB1;
    const float* R1 = ws + O_R1 + (size_t)t*512;
    const float* R2 = ws + O_R2 + (size_t)t*4096;
    float r1c[8];
    #pragma unroll
    for (int j = 0; j < 8; ++j) r1c[j] = R1[j*64 + lane];
    float L = fmaxf((float)node * (5.f/NB), 1e-6f);
    float ur = L*0.2f;
    float ef[8], dd[8];
    if (ur < 1.f){
      float u2=ur*ur, u4=u2*u2, u5=u4*ur;
      float fc = 1.f - 21.f*u5 + 35.f*u5*ur - 15.f*u5*u2;
      float omu = 1.f - ur;
      float dfc = -105.f*u4*omu*omu;
      float invr = 1.f/(L + 1e-9f);
      #pragma unroll
      for (int bb = 0; bb < 8; ++bb){
        float nb = (float)(bb+1);
        float arg = nb*PI_F*ur;
        float sn = __sinf(arg), cs = __cosf(arg);
        float bes = KBES*sn*invr;
        float dbes = KBES*(nb*PI_F*0.2f)*cs*invr - bes*invr;
        ef[bb] = bes*fc;
        dd[bb] = dbes*fc + bes*dfc*0.2f;
      }
    } else {
      #pragma unroll
      for (int bb = 0; bb < 8; ++bb){ ef[bb] = 0.f; dd[bb] = 0.f; }
    }
    float a = 0.f, tt = 0.f;
    #pragma unroll
    for (int bb = 0; bb < 8; ++bb){ a = fmaf(ef[bb], r1c[bb], a); tt = fmaf(r1c[bb], dd[bb], tt); }
    float sg = 1.f/(1.f + __expf(-a));
    float sl = a*sg;
    float q  = sg*fmaf(a, 1.f - sg, 1.f)*tt;
    float r2c[64];
    #pragma unroll
    for (int j = 0; j < 64; ++j) r2c[j] = R2[j*64 + lane];
    float W0=0.f, W1=0.f, Q0=0.f, Q1=0.f;
    #pragma unroll
    for (int j = 0; j < 64; j += 2){
      W0 = fmaf(rlane(sl, j  ), r2c[j  ], W0);
      W1 = fmaf(rlane(sl, j+1), r2c[j+1], W1);
      Q0 = fmaf(rlane(q,  j  ), r2c[j  ], Q0);
      Q1 = fmaf(rlane(q,  j+1), r2c[j+1], Q1);
    }
    size_t idx = ((size_t)t*NB1 + node)*64 + lane;
    ws[O_TW + idx] = (W0+W1)*(1.f/16.f);   // fold /AVG_NEIGH into table
    ws[O_TQ + idx] = (Q0+Q1)*(1.f/16.f);
  } else if (b < GEOM_B + TAB_B + INIT_B){
    int lane = threadIdx.x & 63;
    int n = (b - GEOM_B - TAB_B)*4 + (threadIdx.x >> 6);
    if (n >= NN) return;
    const float* attrs = ws + OFF_ATT;
    float acc = 0.f;
    #pragma unroll
    for (int z = 0; z < NZ; ++z) acc = fmaf(attrs[(size_t)n*NZ+z], ws[O_WEMB + z*64 + lane], acc);
    ws[OFF_NF0 + (size_t)n*64 + lane] = acc;
    if (lane == 0){
      float e = 0.f;
      #pragma unroll
      for (int z = 0; z < NZ; ++z) e = fmaf(attrs[(size_t)n*NZ+z], ws[O_AE + z], e);
      ws[O_E0N + n] = e;
    }
  } else {
    // only 5 transposed matrices are ever consumed
    int i = (b - GEOM_B - TAB_B - INIT_B)*256 + threadIdx.x;   // 0..20479
    int mat = i >> 12, r = (i >> 6) & 63, c = i & 63;
    const size_t src[5] = {O_WMIX, O_WMIX+12288, O_WPROD, O_WPROD+12288, O_WSC+12288};
    const size_t dst[5] = {O_WMIXT, O_WMIXT+12288, O_WPRODT, O_WPRODT+12288, O_WSCT+12288};
    ws[dst[mat] + (size_t)c*64 + r] = ws[src[mat] + (size_t)r*64 + c];
  }
}

// ================= single-pass dual prefix scan (1024 threads) =================
__global__ __launch_bounds__(1024) void k_csr_scan(
    int* __restrict__ curr, int* __restrict__ curs,
    int* __restrict__ offr, int* __restrict__ offs_){
  __shared__ unsigned short cr[NN], cs[NN];
  __shared__ int pr[1024], ps[1024];
  int tid = threadIdx.x;
  for (int i = tid; i < NN; i += 1024){
    cr[i] = (unsigned short)curr[i];
    cs[i] = (unsigned short)curs[i];
  }
  __syncthreads();
  const int chunk = (NN + 1023)/1024;  // 10
  int lo = tid*chunk, hi = lo + chunk;
  if (hi > NN) hi = NN;
  if (lo > NN) lo = NN;
  int sr = 0, ss = 0;
  for (int i = lo; i < hi; ++i){ sr += cr[i]; ss += cs[i]; }
  pr[tid] = sr; ps[tid] = ss;
  __syncthreads();
  for (int o = 1; o < 1024; o <<= 1){
    int vr = (tid >= o) ? pr[tid-o] : 0;
    int vs = (tid >= o) ? ps[tid-o] : 0;
    __syncthreads();
    pr[tid] += vr; ps[tid] += vs;
    __syncthreads();
  }
  int runr = tid ? pr[tid-1] : 0;
  int runs = tid ? ps[tid-1] : 0;
  for (int i = lo; i < hi; ++i){
    int a = cr[i], c = cs[i];
    offr[i] = runr; curr[i] = runr; runr += a;
    offs_[i] = runs; curs[i] = runs; runs += c;
  }
  if (tid == 1023){ offr[NN] = runr; offs_[NN] = runs; }
}

// ---------- fill: live edges only, 32B packed records {ux,uy,uz,L,s,r,e,pad} ----------
__global__ void k_csr_fill(const int* __restrict__ ei, const float* __restrict__ uvl,
                           int* __restrict__ curr, int* __restrict__ curs,
                           float* __restrict__ recr, float* __restrict__ recs){
  int e = blockIdx.x*256 + threadIdx.x;
  if (e >= NE) return;
  float4 q = *(const float4*)(uvl + (size_t)e*4);
  if (q.w >= 5.f) return;
  int s = ei[e], r = ei[NE + e];
  int4 meta; meta.x = s; meta.y = r; meta.z = e; meta.w = 0;
  int pr = atomicAdd(&curr[r], 1);
  *(float4*)(recr + (size_t)pr*8) = q;
  *(int4*)(recr + (size_t)pr*8 + 4) = meta;
  int ps = atomicAdd(&curs[s], 1);
  *(float4*)(recs + (size_t)ps*8) = q;
  *(int4*)(recs + (size_t)ps*8 + 4) = meta;
}

// ================= aggregation: 8-record coalesced group loads + readlane broadcast =================
__global__ __launch_bounds__(256) void k_agg(
    const float* __restrict__ TWt, const float* __restrict__ recr,
    const float* __restrict__ h, const int* __restrict__ offr,
    float* __restrict__ agg){
  int lane = threadIdx.x & 63;
  int wid = blockIdx.x*4 + (threadIdx.x >> 6);
  int nw  = gridDim.x*4;
  for (int n = wid; n < NN; n += nw){
    int lo = offr[n], hi = offr[n+1];
    float c0=0.f, x1=0.f, y1=0.f, z1=0.f;
    for (int i = lo; i < hi; i += 8){
      float rv = recr[(size_t)i*8 + lane];   // 8 records = 64 floats, coalesced
      int cnt = hi - i;
      if (cnt >= 8){
        #pragma unroll
        for (int j = 0; j < 8; ++j){
          float ux = rlane(rv, j*8+0), uy = rlane(rv, j*8+1), uz = rlane(rv, j*8+2);
          float L  = rlane(rv, j*8+3);
          int   s  = irlane(rv, j*8+4);
          float pos = L*(NB/5.f); int bi = (int)pos; float f = pos - (float)bi;
          const float* T = TWt + (size_t)bi*64 + lane;
          float t0 = T[0];
          float w = fmaf(T[64]-t0, f, t0);
          float wh = w * h[(size_t)s*64 + lane];
          c0 += wh;
          x1 = fmaf(wh, ux, x1);
          y1 = fmaf(wh, uy, y1);
          z1 = fmaf(wh, uz, z1);
        }
      } else {
        for (int j = 0; j < cnt; ++j){
          float ux = rlane(rv, j*8+0), uy = rlane(rv, j*8+1), uz = rlane(rv, j*8+2);
          float L  = rlane(rv, j*8+3);
          int   s  = irlane(rv, j*8+4);
          float pos = L*(NB/5.f); int bi = (int)pos; float f = pos - (float)bi;
          const float* T = TWt + (size_t)bi*64 + lane;
          float t0 = T[0];
          float w = fmaf(T[64]-t0, f, t0);
          float wh = w * h[(size_t)s*64 + lane];
          c0 += wh;
          x1 = fmaf(wh, ux, x1);
          y1 = fmaf(wh, uy, y1);
          z1 = fmaf(wh, uz, z1);
        }
      }
    }
    size_t ob = (size_t)n*64 + lane;
    agg[ob]        = c0;               // table pre-scaled by 1/16
    agg[ob+PL]     = S3*x1;
    agg[ob+2*PL]   = S3*y1;
    agg[ob+3*PL]   = S3*z1;
  }
}

// ================= per-l linear (mix), plane-major; GB1 fuses t=1 gback into y==0 =================
template<int GB1>
__global__ __launch_bounds__(256, 3) void k_lin2(
    const float* __restrict__ in, const float* __restrict__ W3, float* __restrict__ out,
    const float* __restrict__ WMIXT1, const float* __restrict__ WPRODT1,
    const float* __restrict__ we1, const float* __restrict__ wp1,
    float* __restrict__ ga1){
  int k = blockIdx.y;
  int l = (k==0) ? 0 : 1;
  const float* W = W3 + (size_t)l*4096;
  int lane = threadIdx.x & 63;
  float wcol[64];
  #pragma unroll
  for (int j = 0; j < 64; ++j) wcol[j] = W[j*64 + lane];
  float wcol2[64];
  float g = 0.f, p0 = 0.f, p1 = 0.f, p2 = 0.f;
  const bool gb1 = GB1 && (k == 0);
  if (gb1){
    #pragma unroll
    for (int j = 0; j < 64; ++j) wcol2[j] = WMIXT1[j*64 + lane];
    #pragma unroll
    for (int c = 0; c < 64; ++c) g = fmaf(we1[c], WPRODT1[c*64 + lane], g);
    p0 = wp1[lane*3]; p1 = wp1[lane*3+1]; p2 = wp1[lane*3+2];
  }
  int wid = blockIdx.x*4 + (threadIdx.x >> 6);
  int nw  = gridDim.x*4;
  const float* inp = in + (size_t)k*PL;
  float* outp = out + (size_t)k*PL;
  for (int n = wid; n < NN; n += nw){
    float x = inp[(size_t)n*64 + lane];
    float a0 = 0.f, a1 = 0.f, a2 = 0.f, a3 = 0.f;
    #pragma unroll
    for (int j = 0; j < 64; j += 4){
      a0 = fmaf(rlane(x, j  ), wcol[j  ], a0);
      a1 = fmaf(rlane(x, j+1), wcol[j+1], a1);
      a2 = fmaf(rlane(x, j+2), wcol[j+2], a2);
      a3 = fmaf(rlane(x, j+3), wcol[j+3], a3);
    }
    float m = (a0+a1) + (a2+a3);
    outp[(size_t)n*64 + lane] = m;
    if (gb1){
      // fused gback1: GA1 = (g * d/ds0[s0*poly(s0)]) @ WMIXT1, s0 = m
      float poly = fmaf(fmaf(p2, m, p1), m, p0);
      float dp   = fmaf(2.f*p2, m, p1);
      float gb = g*fmaf(m, dp, poly);
      float b0=0.f, b1=0.f, b2=0.f, b3=0.f;
      #pragma unroll
      for (int j = 0; j < 64; j += 4){
        b0 = fmaf(rlane(gb, j  ), wcol2[j  ], b0);
        b1 = fmaf(rlane(gb, j+1), wcol2[j+1], b1);
        b2 = fmaf(rlane(gb, j+2), wcol2[j+2], b2);
        b3 = fmaf(rlane(gb, j+3), wcol2[j+3], b3);
      }
      ga1[(size_t)n*64 + lane] = (b0+b1) + (b2+b3);
    }
  }
}

// ================= fused layer tail (plane-major; compile-time variants) =================
template<int WRITE_NF, int NF_SINGLE>
__global__ __launch_bounds__(256, 3) void k_tail(
    const float* __restrict__ nf_in, const float* __restrict__ msg,
    const float* __restrict__ Wsc, const float* __restrict__ Wprod, const float* __restrict__ wp,
    const float* __restrict__ we, const float* __restrict__ wd,
    float* __restrict__ nf_out, float* __restrict__ en, float* __restrict__ adp){
  int lane = threadIdx.x & 63;
  int k = threadIdx.x >> 6;
  int l = (k==0) ? 0 : 1;
  const bool use_sc = !(NF_SINGLE && k > 0);
  float wcs[64], wcp[64];
  #pragma unroll
  for (int j = 0; j < 64; ++j)
    wcp[j] = Wprod[(size_t)l*4096 + j*64 + lane];
  if (use_sc){
    #pragma unroll
    for (int j = 0; j < 64; ++j)
      wcs[j] = Wsc[(size_t)l*4096 + j*64 + lane];
  }
  float p0 = wp[lane*3], p1 = wp[lane*3+1], p2 = wp[lane*3+2];
  float rw = (k==0) ? we[lane] : wd[lane];
  const float* msgk = msg + (size_t)k*PL;
  const float* nfk  = nf_in + (size_t)k*PL;
  float* outk = nf_out + (size_t)k*PL;
  for (int n = blockIdx.x; n < NN; n += gridDim.x){
    size_t base = (size_t)n*64 + lane;
    float s0 = msg[base];
    float xm = (k==0) ? s0 : msgk[base];
    float xg = xm * fmaf(fmaf(p2, s0, p1), s0, p0);
    float b0=0.f, b1=0.f;
    #pragma unroll
    for (int j = 0; j < 64; j += 2){
      b0 = fmaf(rlane(xg, j  ), wcp[j  ], b0);
      b1 = fmaf(rlane(xg, j+1), wcp[j+1], b1);
    }
    float out = b0 + b1;
    if (use_sc){
      float xs = nfk[base];
      float a0=0.f, a1=0.f;
      #pragma unroll
      for (int j = 0; j < 64; j += 2){
        a0 = fmaf(rlane(xs, j  ), wcs[j  ], a0);
        a1 = fmaf(rlane(xs, j+1), wcs[j+1], a1);
      }
      out += a0 + a1;
    }
    if (WRITE_NF) outk[base] = out;
    float red = out * rw;
    #pragma unroll
    for (int o = 32; o; o >>= 1) red += __shfl_xor(red, o, 64);
    if (lane == 0){
      if (k == 0) en[n] = red;
      else        adp[n*3 + (k-1)] += red;
    }
  }
}

// ================= fused ghgather0 + gback0 (+ bwd_head) + segmented reduce =================
static constexpr int GHG_GRID = 1024;
static constexpr int RED_B = (NN+255)/256;    // 40
__global__ __launch_bounds__(256) void k_ghg0(float* __restrict__ ws, const int* __restrict__ offs_,
                                              const int* __restrict__ batch){
  __shared__ float wl[2*4096];   // [0]=WPRODT0 l0, [1]=WMIXT0 l0
  if (blockIdx.x >= GHG_GRID){
    // ---- folded k_reduce (inputs ready after k_tail<t=1>) ----
    int n = (blockIdx.x - GHG_GRID)*256 + threadIdx.x;
    int lane = threadIdx.x & 63;
    bool valid = (n < NN);
    int g = valid ? batch[n] : -1;
    float v0=0.f, v1=0.f, v2=0.f, tx=0.f, ty=0.f, tz=0.f;
    if (valid){
      v0 = ws[O_E0N + n]; v1 = ws[O_EN0 + n]; v2 = ws[O_EN1 + n];
      float qq = ws[OFF_CHG + n];
      tx = ws[O_ADP + n*3+0] + qq*ws[OFF_PIN + n*3+0];
      ty = ws[O_ADP + n*3+1] + qq*ws[OFF_PIN + n*3+1];
      tz = ws[O_ADP + n*3+2] + qq*ws[OFF_PIN + n*3+2];
    }
    float* e0g = ws + O_E0G; float* Etg = ws + O_ETG; float* td = ws + O_TD;
    int g0 = __shfl(g, 0, 64), g63 = __shfl(g, 63, 64);
    if (g0 == g63 && g0 >= 0){
      #pragma unroll
      for (int o = 32; o; o >>= 1){
        v0 += __shfl_xor(v0, o, 64); v1 += __shfl_xor(v1, o, 64); v2 += __shfl_xor(v2, o, 64);
        tx += __shfl_xor(tx, o, 64); ty += __shfl_xor(ty, o, 64); tz += __shfl_xor(tz, o, 64);
      }
      if (lane == 0){
        atomicAdd(&e0g[g0], v0); atomicAdd(&Etg[g0], v1); atomicAdd(&Etg[16+g0], v2);
        atomicAdd(&td[g0*3+0], tx); atomicAdd(&td[g0*3+1], ty); atomicAdd(&td[g0*3+2], tz);
      }
    } else if (valid){
      atomicAdd(&e0g[g], v0); atomicAdd(&Etg[g], v1); atomicAdd(&Etg[16+g], v2);
      atomicAdd(&td[g*3+0], tx); atomicAdd(&td[g*3+1], ty); atomicAdd(&td[g*3+2], tz);
    }
    return;
  }
  for (int i = threadIdx.x; i < 4096; i += 256){
    wl[i]        = ws[O_WPRODT + i];
    wl[4096 + i] = ws[O_WMIXT + i];
  }
  __syncthreads();
  const int lane = threadIdx.x & 63;
  int wid = blockIdx.x*4 + (threadIdx.x >> 6);
  const int nw = GHG_GRID*4;
  // gnfc = we0 + WSCT1 @ we1  (folded bwd_head)
  float gnfc = ws[O_WE + lane];
  {
    const float* WS1 = ws + O_WSCT + 12288;
    const float* we1 = ws + O_WE + 64;
    #pragma unroll
    for (int c = 0; c < 64; ++c) gnfc = fmaf(we1[c], WS1[c*64 + lane], gnfc);
  }
  const float p0 = ws[O_WPOLY + lane*3];
  const float p1 = ws[O_WPOLY + lane*3 + 1];
  const float p2 = ws[O_WPOLY + lane*3 + 2];
  const float* TW1 = ws + O_TW + (size_t)NB1*64;  // t=1 table (pre-scaled 1/16)
  const float* recs = ws + O_RECS;
  const float* GA1 = ws + O_GA1;
  for (int n = wid; n < NN; n += nw){
    int lo = offs_[n], hi = offs_[n+1];
    float acc = 0.f;
    for (int i = lo; i < hi; i += 8){
      float rv = recs[(size_t)i*8 + lane];   // 8 records coalesced
      int cnt = hi - i;
      if (cnt >= 8){
        #pragma unroll
        for (int j = 0; j < 8; ++j){
          float L = rlane(rv, j*8+3);
          int   r = irlane(rv, j*8+5);
          float pos = L*(NB/5.f); int bi = (int)pos; float f = pos - (float)bi;
          const float* T = TW1 + (size_t)bi*64 + lane;
          float t0 = T[0];
          float w = fmaf(T[64]-t0, f, t0);
          acc = fmaf(w, GA1[(size_t)r*64 + lane], acc);
        }
      } else {
        for (int j = 0; j < cnt; ++j){
          float L = rlane(rv, j*8+3);
          int   r = irlane(rv, j*8+5);
          float pos = L*(NB/5.f); int bi = (int)pos; float f = pos - (float)bi;
          const float* T = TW1 + (size_t)bi*64 + lane;
          float t0 = T[0];
          float w = fmaf(T[64]-t0, f, t0);
          acc = fmaf(w, GA1[(size_t)r*64 + lane], acc);
        }
      }
    }
    float gB = gnfc + acc;                // table pre-scaled by 1/16
    float q0=0.f, q1=0.f;
    #pragma unroll
    for (int j = 0; j < 64; j += 2){
      q0 = fmaf(rlane(gB,j),   wl[j*64 + lane],     q0);
      q1 = fmaf(rlane(gB,j+1), wl[(j+1)*64 + lane], q1);
    }
    float gmp = q0 + q1;
    float s0v = ws[OFF_MSG0 + (size_t)n*64 + lane];
    float poly = fmaf(fmaf(p2, s0v, p1), s0v, p0);
    float dp   = fmaf(2.f*p2, s0v, p1);
    float gb = gmp * fmaf(s0v, dp, poly);
    float u0=0.f, u1=0.f;
    #pragma unroll
    for (int j = 0; j < 64; j += 2){
      u0 = fmaf(rlane(gb,j),   wl[4096 + j*64 + lane],     u0);
      u1 = fmaf(rlane(gb,j+1), wl[4096 + (j+1)*64 + lane], u1);
    }
    ws[O_GA0 + (size_t)n*64 + lane] = u0 + u1;
  }
}

// ================= fused edge backward + force scatter: 8-edge groups =================
__global__ __launch_bounds__(256) void k_bwdE2(float* __restrict__ ws, const int* __restrict__ nlive_ptr){
  const int lane = threadIdx.x & 63;
  int wid = blockIdx.x*4 + (threadIdx.x >> 6);
  const int nw = gridDim.x*4;
  const int nlive = nlive_ptr[0];
  const int ngrp = (nlive + 7) >> 3;
  const float* recs = ws + O_RECS;
  const float* TQ  = ws + O_TQ;     // pre-scaled 1/16
  const float* h0  = ws + OFF_NF0;
  const float* h1  = ws + OFF_NF1;  // plane 0
  const float* ga0 = ws + O_GA0;
  const float* ga1 = ws + O_GA1;
  float* gpos = ws + O_GPOS;
  for (int gi = wid; gi < ngrp; gi += nw){
    const int i0 = gi*8;
    float rv = recs[(size_t)i0*8 + lane];   // 8 records coalesced
    int cnt = nlive - i0; if (cnt > 8) cnt = 8;
    #pragma unroll 8
    for (int j = 0; j < cnt; ++j){
      float ux = rlane(rv, j*8+0), uy = rlane(rv, j*8+1), uz = rlane(rv, j*8+2);
      float L  = rlane(rv, j*8+3);
      int   s  = irlane(rv, j*8+4);
      int   r  = irlane(rv, j*8+5);
      float pos = L*(NB/5.f); int bi = (int)pos; float f = pos - (float)bi;
      const float* T0 = TQ + (size_t)bi*64 + lane;
      const float* T1 = T0 + (size_t)NB1*64;
      float Q0 = fmaf(T0[64]-T0[0], f, T0[0]);
      float Q1 = fmaf(T1[64]-T1[0], f, T1[0]);
      float rr = Q0*h0[(size_t)s*64 + lane]*ga0[(size_t)r*64 + lane]
               + Q1*h1[(size_t)s*64 + lane]*ga1[(size_t)r*64 + lane];
      #pragma unroll
      for (int o = 32; o; o >>= 1) rr += __shfl_xor(rr, o, 64);
      if (lane < 3){
        float u = (lane==0) ? ux : ((lane==1) ? uy : uz);
        float v = rr*u;
        atomicAdd(&gpos[(size_t)s*3 + lane],  v);
        atomicAdd(&gpos[(size_t)r*3 + lane], -v);
      }
    }
  }
}

__global__ void k_writeout(const float* __restrict__ e0g, const float* __restrict__ Etg,
                           const float* __restrict__ td, const float* __restrict__ adp,
                           const float* __restrict__ gpos, void* __restrict__ outv,
                           const int* __restrict__ flag){
  int i = blockIdx.x*256 + threadIdx.x;
  const int total = NG + NG*3 + NN*3 + NG*3 + NN*3; // 60112
  if (i >= total) return;
  float v;
  if (i < 16){
    v = e0g[i] + Etg[i] + Etg[16+i];
  } else if (i < 64){
    int j = i - 16; int g = j/3, t = j - g*3;
    v = (t == 0) ? e0g[g] : Etg[(t-1)*16 + g];
  } else if (i < 64 + NN*3){
    v = -gpos[i-64];
  } else if (i < 64 + NN*3 + 48){
    v = td[i - (64 + NN*3)];
  } else {
    v = adp[i - (64 + NN*3 + 48)];
  }
  if (flag[0]) ((__hip_bfloat16*)outv)[i] = __float2bfloat16(v);
  else         ((float*)outv)[i] = v;
}

extern "C" void kernel_launch(void* const* d_in, const int* in_sizes, int n_in,
                              void* d_out, int out_size, void* d_ws, size_t ws_size,
                              hipStream_t stream) {
  if (ws_size < WS_FLOATS*sizeof(float)) return; // ~62 MB
  const int* ei    = (const int*)d_in[14];
  const int* batch = (const int*)d_in[15];
  float* ws = (float*)d_ws;

  int* offr  = (int*)(ws + O_OFFR);
  int* offs_ = (int*)(ws + O_OFFS);
  int* curr  = (int*)(ws + O_CURR);
  int* curs  = (int*)(ws + O_CURS);

  // workspace zeroing folded into k_load_all's tail blocks (no memset dispatches)
  k_load_all<<<LD_B + Z1_B + Z2_B, 256, 0, stream>>>(
      d_in[0], d_in[1], d_in[2], d_in[3], d_in[4], d_in[5], d_in[6], d_in[7],
      d_in[8], d_in[9], d_in[10], d_in[11], d_in[12], d_in[13], ws);
  k_prep<<<GEOM_B + TAB_B + INIT_B + TRAN_B, 256, 0, stream>>>(ws, ei);
  k_csr_scan<<<1, 1024, 0, stream>>>(curr, curs, offr, offs_);
  k_csr_fill<<<(NE+255)/256, 256, 0, stream>>>(ei, ws+OFF_UVL, curr, curs,
                                               ws+O_RECR, ws+O_RECS);

  dim3 ling(256, 4);

  // ---------- forward t=0 ----------
  k_agg<<<1024, 256, 0, stream>>>(ws+O_TW, ws+O_RECR, ws+OFF_NF0, offr, ws+OFF_AGG);
  k_lin2<0><<<ling, 256, 0, stream>>>(ws+OFF_AGG, ws+O_WMIX, ws+OFF_MSG0,
                                      ws, ws, ws, ws, ws);
  k_tail<1,1><<<1024, 256, 0, stream>>>(ws+OFF_NF0, ws+OFF_MSG0,
                                        ws+O_WSC, ws+O_WPROD,
                                        ws+O_WPOLY, ws+O_WE, ws+O_WD,
                                        ws+OFF_NF1, ws+O_EN0, ws+O_ADP);
  // ---------- forward t=1 (+ fused gback1 in y==0) ----------
  k_agg<<<1024, 256, 0, stream>>>(ws+O_TW + (size_t)NB1*64, ws+O_RECR, ws+OFF_NF1, offr, ws+OFF_AGG);
  k_lin2<1><<<ling, 256, 0, stream>>>(ws+OFF_AGG, ws+O_WMIX + 12288, ws+OFF_MSG1,
                                      ws+O_WMIXT + 12288, ws+O_WPRODT + 12288,
                                      ws+O_WE + 64, ws+O_WPOLY + 192, ws+O_GA1);
  k_tail<0,0><<<1024, 256, 0, stream>>>(ws+OFF_NF1, ws+OFF_MSG1,
                                        ws+O_WSC + 12288, ws+O_WPROD + 12288,
                                        ws+O_WPOLY + 192, ws+O_WE + 64, ws+O_WD + 64,
                                        ws+OFF_NF1, ws+O_EN1, ws+O_ADP);

  // ---------- backward ----------
  k_ghg0<<<GHG_GRID + RED_B, 256, 0, stream>>>(ws, offs_, batch);
  k_bwdE2<<<2048, 256, 0, stream>>>(ws, offs_ + NN);

  k_writeout<<<(60112+255)/256, 256, 0, stream>>>(ws+O_E0G, ws+O_ETG, ws+O_TD, ws+O_ADP,
                                                  ws+O_GPOS, d_out, (const int*)(ws+O_FLAG));
}